// Round 13
// baseline (409.761 us; speedup 1.0000x reference)
//
#include <hip/hip_runtime.h>
#include <hip/hip_bf16.h>
#include <math.h>

#define TT 2000
#define NN 256
#define DD 256
#define SS 45
#define SOUT 48
#define NTRANS_C 40
#define CHUNKS 40
#define CLEN 50   // TT / CHUNKS
#define BK 32     // x K-chunk (floats)
#define NCH (DD / BK)   // 8 chunks
#define REP_A 4   // 1 real pass + 3 measurement-only K-loop passes

typedef __attribute__((ext_vector_type(8))) short bf16x8;
typedef __attribute__((ext_vector_type(4))) float f32x4;
typedef __attribute__((ext_vector_type(4))) int i32x4;

#define AS1 __attribute__((address_space(1)))
#define AS3 __attribute__((address_space(3)))

__device__ __forceinline__ void gload_lds16(const float* g, float* l) {
    __builtin_amdgcn_global_load_lds((const AS1 void*)g, (AS3 void*)l, 16, 0, 0);
}

__device__ inline ushort f2bf_rne(float f) {
    unsigned u = __float_as_uint(f);
    unsigned r = u + 0x7fffu + ((u >> 16) & 1u);
    return (ushort)(r >> 16);
}
// packed f32x2 -> bf16x2 (RNE), single HW instr [T12]
__device__ __forceinline__ int cvtpk(float lo, float hi) {
    int r;
    asm("v_cvt_pk_bf16_f32 %0, %1, %2" : "=v"(r) : "v"(lo), "v"(hi));
    return r;
}
// score-buffer storage permutation (kB reads b64+b32)
__device__ __host__ __forceinline__ constexpr int sidx(int c) {
    return (c < 32) ? (4 * (c & 7) + (c >> 3))
         : (c < 36) ? (32 + 2 * (c - 32))
         : (c < 40) ? (32 + 2 * (c - 36) + 1)
         : c;
}
// LDS W swizzle: 16B slot index XORed with (row&7); idx in ushorts.
__device__ __forceinline__ int swz_idx(int s, int koff) {
    return s * DD + ((((koff >> 3) ^ (s & 7)) << 3) | (koff & 7));
}

// ---------------- Prep: W -> bf16 (RNE), pad to 48 rows; pad b ----------
__global__ __launch_bounds__(256) void kPrep(const float* __restrict__ W,
                                             const float* __restrict__ b,
                                             ushort* __restrict__ Whi,
                                             float* __restrict__ b48) {
    const int s = blockIdx.x;   // 0..47
    const int k = threadIdx.x;  // 0..255
    const float wv = (s < SS) ? W[s * DD + k] : 0.f;
    Whi[s * DD + k] = f2bf_rne(wv);
    if (k == 0) b48[s] = (s < SS) ? b[s] : 0.f;
}

// ---------------- Kernel A: R10 + inert measurement passes ---------------
// Real pass + epilogue identical to R10. Then 3 wave-private K-loop-only
// passes into a sunk accumulator (no stores, no barriers) to surface kA's
// steady-state counters in rocprof's top-5.
__global__ __launch_bounds__(512, 4) void kA_mfma(const float* __restrict__ x,
                                                  const ushort* __restrict__ Whi,
                                                  const float* __restrict__ b48,
                                                  ushort* __restrict__ sc) {
    __shared__ ushort Wl[SOUT * DD];        // 24 KB, slot-swizzled
    __shared__ float xb[3][128 * BK];       // 3 x 16 KB, wave-sliced
    const int tid = threadIdx.x;
    // stage W once
    for (int idx = tid; idx < SOUT * (DD / 8); idx += 512) {
        const int s = idx >> 5;
        const int c8 = (idx & 31) * 8;
        const uint4 v = *reinterpret_cast<const uint4*>(Whi + s * DD + c8);
        *reinterpret_cast<uint4*>(&Wl[swz_idx(s, c8)]) = v;
    }
    __syncthreads();

    const int l = tid & 63, w = tid >> 6;
    const long m0 = (long)blockIdx.x * 128;
    const int r16 = l & 15;   // A row / C col
    const int kg = l >> 4;    // k-group 0..3
    const int lrow = l >> 3;                    // 0..7 (== row&7)
    const int sslot = (l & 7) ^ lrow;           // inverse-swizzled source slot
    const float* xsrc = x + (m0 + w * 16 + lrow) * DD + sslot * 4;

#define STAGE(c)                                                              \
    do {                                                                      \
        float* _d = &xb[(c) % 3][(w * 16) * BK];                              \
        gload_lds16(xsrc + (c) * BK, _d);                                     \
        gload_lds16(xsrc + 8 * DD + (c) * BK, _d + 8 * BK);                   \
    } while (0)

    f32x4 acc[3] = {{0, 0, 0, 0}, {0, 0, 0, 0}, {0, 0, 0, 0}};
    const int rbase = (w * 16 + r16) * BK;
    const int q0 = ((kg * 2) ^ (r16 & 7)) * 4;
    const int q1 = ((kg * 2 + 1) ^ (r16 & 7)) * 4;

    STAGE(0);
    STAGE(1);

#pragma unroll
    for (int c = 0; c < NCH; ++c) {
        if (c + 2 < NCH) STAGE(c + 2);
        if (c < NCH - 2)       asm volatile("s_waitcnt vmcnt(4)" ::: "memory");
        else if (c == NCH - 2) asm volatile("s_waitcnt vmcnt(2)" ::: "memory");
        else                   asm volatile("s_waitcnt vmcnt(0)" ::: "memory");
        __builtin_amdgcn_sched_barrier(0);   // rule #18
        const float* xcur = &xb[c % 3][0];
        const float4 f0 = *reinterpret_cast<const float4*>(xcur + rbase + q0);
        const float4 f1 = *reinterpret_cast<const float4*>(xcur + rbase + q1);
        i32x4 av;
        av[0] = cvtpk(f0.x, f0.y);
        av[1] = cvtpk(f0.z, f0.w);
        av[2] = cvtpk(f1.x, f1.y);
        av[3] = cvtpk(f1.z, f1.w);
        const bf16x8 a = __builtin_bit_cast(bf16x8, av);
        const int koff = c * BK + kg * 8;
        const bf16x8 b0 = *reinterpret_cast<const bf16x8*>(&Wl[swz_idx(0 * 16 + r16, koff)]);
        const bf16x8 b1 = *reinterpret_cast<const bf16x8*>(&Wl[swz_idx(1 * 16 + r16, koff)]);
        const bf16x8 b2 = *reinterpret_cast<const bf16x8*>(&Wl[swz_idx(2 * 16 + r16, koff)]);
        acc[0] = __builtin_amdgcn_mfma_f32_16x16x32_bf16(a, b0, acc[0], 0, 0, 0);
        acc[1] = __builtin_amdgcn_mfma_f32_16x16x32_bf16(a, b1, acc[1], 0, 0, 0);
        acc[2] = __builtin_amdgcn_mfma_f32_16x16x32_bf16(a, b2, acc[2], 0, 0, 0);
    }

    // ---- epilogue: LDS-staged coalesced score store (exact R10) ----
    __syncthreads();   // all waves' DMAs retired (each waited vmcnt(0))
    ushort* se = reinterpret_cast<ushort*>(&xb[0][0]);   // 128*48 u16 = 12.3 KB
#pragma unroll
    for (int jt = 0; jt < 3; ++jt) {
        const int col = jt * 16 + r16;
        const float bias = b48[col];
        int si;
        if (jt < 2) si = 4 * (col & 7) + (col >> 3);
        else if (r16 < 8) si = (r16 < 4) ? (32 + 2 * r16) : (32 + 2 * (r16 - 4) + 1);
        else si = 40 + (r16 - 8);
#pragma unroll
        for (int r = 0; r < 4; ++r) {
            const int lr = w * 16 + kg * 4 + r;   // 0..127 (block-local row)
            const float y = acc[jt][r] + bias;
            float v;
            if (col < NTRANS_C) {
                const float e = __expf(2.f * y);
                v = 5.f * (1.f - 2.f / (e + 1.f));   // 5*tanh(y)
            } else {
                v = y;
            }
            se[lr * SOUT + si] = f2bf_rne(v);
        }
    }
    __syncthreads();
    // coalesced burst: 768 uint4 (12.3 KB), 1 KB per wave-instruction
    const uint4* su = reinterpret_cast<const uint4*>(se);
    uint4* du = reinterpret_cast<uint4*>(sc + m0 * SOUT);
    du[tid] = su[tid];
    if (tid < 256) du[512 + tid] = su[512 + tid];

    // ---- measurement-only passes: wave-private, output-free, inert ----
    __syncthreads();   // epilogue LDS reads fully done before xb reuse
    f32x4 a2[3] = {{0, 0, 0, 0}, {0, 0, 0, 0}, {0, 0, 0, 0}};
    for (int rep = 1; rep < REP_A; ++rep) {
        STAGE(0);
        STAGE(1);
#pragma unroll
        for (int c = 0; c < NCH; ++c) {
            if (c + 2 < NCH) STAGE(c + 2);
            if (c < NCH - 2)       asm volatile("s_waitcnt vmcnt(4)" ::: "memory");
            else if (c == NCH - 2) asm volatile("s_waitcnt vmcnt(2)" ::: "memory");
            else                   asm volatile("s_waitcnt vmcnt(0)" ::: "memory");
            __builtin_amdgcn_sched_barrier(0);
            const float* xcur = &xb[c % 3][0];
            const float4 f0 = *reinterpret_cast<const float4*>(xcur + rbase + q0);
            const float4 f1 = *reinterpret_cast<const float4*>(xcur + rbase + q1);
            i32x4 av;
            av[0] = cvtpk(f0.x, f0.y);
            av[1] = cvtpk(f0.z, f0.w);
            av[2] = cvtpk(f1.x, f1.y);
            av[3] = cvtpk(f1.z, f1.w);
            const bf16x8 a = __builtin_bit_cast(bf16x8, av);
            const int koff = c * BK + kg * 8;
            const bf16x8 b0 = *reinterpret_cast<const bf16x8*>(&Wl[swz_idx(0 * 16 + r16, koff)]);
            const bf16x8 b1 = *reinterpret_cast<const bf16x8*>(&Wl[swz_idx(1 * 16 + r16, koff)]);
            const bf16x8 b2 = *reinterpret_cast<const bf16x8*>(&Wl[swz_idx(2 * 16 + r16, koff)]);
            a2[0] = __builtin_amdgcn_mfma_f32_16x16x32_bf16(a, b0, a2[0], 0, 0, 0);
            a2[1] = __builtin_amdgcn_mfma_f32_16x16x32_bf16(a, b1, a2[1], 0, 0, 0);
            a2[2] = __builtin_amdgcn_mfma_f32_16x16x32_bf16(a, b2, a2[2], 0, 0, 0);
        }
    }
    // keep the measurement passes live without any output (rule #17)
    asm volatile("" :: "v"(a2[0]), "v"(a2[1]), "v"(a2[2]));
#undef STAGE
}

// ---------------- DPP / swizzle cross-lane helpers -----------------------
#define DPP_XOR1 0xB1  // quad_perm(1,0,3,2)
#define DPP_XOR2 0x4E  // quad_perm(2,3,0,1)

__device__ inline float fmax_x1(float v) {
    const int d = __builtin_amdgcn_mov_dpp(__float_as_int(v), DPP_XOR1, 0xF, 0xF, true);
    return fmaxf(v, __int_as_float(d));
}
__device__ inline float fmax_x2(float v) {
    const int d = __builtin_amdgcn_mov_dpp(__float_as_int(v), DPP_XOR2, 0xF, 0xF, true);
    return fmaxf(v, __int_as_float(d));
}
__device__ inline float add_x1(float v) {
    const int d = __builtin_amdgcn_mov_dpp(__float_as_int(v), DPP_XOR1, 0xF, 0xF, true);
    return v + __int_as_float(d);
}
__device__ inline float add_x2(float v) {
    const int d = __builtin_amdgcn_mov_dpp(__float_as_int(v), DPP_XOR2, 0xF, 0xF, true);
    return v + __int_as_float(d);
}
__device__ inline float swz4(float v) {   // lane ^ 4
    return __int_as_float(__builtin_amdgcn_ds_swizzle(__float_as_int(v), 0x101F));
}
__device__ inline float fmax_x4(float v) { return fmaxf(v, swz4(v)); }
__device__ inline float add_x4(float v) { return v + swz4(v); }
__device__ inline float sum8(float v) { return add_x4(add_x2(add_x1(v))); }
__device__ inline float max8(float v) { return fmax_x4(fmax_x2(fmax_x1(v))); }
__device__ inline float gat_k(float v) {
    return __int_as_float(__builtin_amdgcn_ds_swizzle(__float_as_int(v), 0x001B));
}

// ---------------- Kernel B: per-(n,chunk) 8x8 log transfer matrix ----------
__global__ __launch_bounds__(64) void kB_scan(const ushort* __restrict__ sc,
                                              float* __restrict__ gbuf) {
    const int n = blockIdx.x;
    const int c = blockIdx.y;
    const int l = threadIdx.x;
    const int col = l >> 3;
    const int j = l & 7;
    const int k = j & 3;
    float m = (j == col) ? 0.f : -60.f;   // finite "-inf"
    const long stride = (long)NN * SOUT;  // in u16 elements
    const ushort* sp = sc + ((long)(c * CLEN) * NN + n) * SOUT;

    uint2 dv = *reinterpret_cast<const uint2*>(sp + 4 * j);
    unsigned dab = *reinterpret_cast<const unsigned*>(sp + 32 + 2 * k);

    for (int t = 0; t < CLEN; ++t) {
        const ushort* np = sp + stride;
        uint2 nv;
        unsigned nab;
        if (t + 1 < CLEN) {   // prefetch next step's scores
            nv = *reinterpret_cast<const uint2*>(np + 4 * j);
            nab = *reinterpret_cast<const unsigned*>(np + 32 + 2 * k);
        }
        const float c0 = __uint_as_float(dv.x << 16);
        const float c1 = __uint_as_float(dv.x & 0xffff0000u);
        const float c2 = __uint_as_float(dv.y << 16);
        const float c3 = __uint_as_float(dv.y & 0xffff0000u);
        const float ca = __uint_as_float(dab << 16);
        const float cb = __uint_as_float(dab & 0xffff0000u);
        const float E0 = __expf(c0), E1 = __expf(c1), E2 = __expf(c2), E3 = __expf(c3);
        const float Ea = __expf(ca), Eb = __expf(cb);
        const float Mq = fmax_x2(fmax_x1(m));   // quad-local max (2 DPP)
        const float MqX = swz4(Mq);             // other quad's max (parallel)
        const float e = __expf(m - Mq);
        const float corr = __expf(MqX - Mq);    // cross-quad rescale
        const float p0l = add_x2(add_x1(e * E0));
        const float p1l = add_x2(add_x1(e * E1));
        const float p2l = add_x2(add_x1(e * E2));
        const float p3l = add_x2(add_x1(e * E3));
        const float p0 = fmaf(corr, swz4(p0l), p0l);
        const float p1 = fmaf(corr, swz4(p1l), p1l);
        const float p2 = fmaf(corr, swz4(p2l), p2l);
        const float p3 = fmaf(corr, swz4(p3l), p3l);
        const float Sb = fmaf(corr * gat_k(e), Ea, e * Eb);
        const float Slow = (j < 2) ? ((j == 0) ? p0 : p1)
                                   : ((j == 2) ? p2 : p3);
        const float S = (j < 4) ? Slow : Sb;
        m = Mq + __logf(S);
        dv = nv; dab = nab;
        sp = np;
    }
    gbuf[((long)(n * CHUNKS + c)) * 64 + l] = m;
}

// ---------------- butterfly lse helpers for kC ----------------
__device__ inline float lse8(float v) {
    const float m = max8(v);
    return m + __logf(sum8(__expf(v - m)));
}
__device__ inline float lse64(float v) {
    float m = v;
#pragma unroll
    for (int d = 1; d < 64; d <<= 1) m = fmaxf(m, __shfl_xor(m, d));
    float e = __expf(v - m);
#pragma unroll
    for (int d = 1; d < 64; d <<= 1) e += __shfl_xor(e, d);
    return m + __logf(e);
}

// ---------------- Kernel C: fold chunk matrices, emit logZ/T -------------
__global__ __launch_bounds__(64) void kC_combine(const float* __restrict__ gbuf,
                                                 float* __restrict__ logZT) {
    const int n = blockIdx.x;
    const int l = threadIdx.x;
    const int gi = (l & 7) * 8 + (l >> 3);
    float g[CHUNKS];
#pragma unroll
    for (int c = 0; c < CHUNKS; ++c)
        g[c] = gbuf[((long)(n * CHUNKS + c)) * 64 + gi];
    float u = -logf(8.f);
#pragma unroll
    for (int c = 0; c < CHUNKS; ++c) {
        const float nu = lse8(g[c] + u);
        u = __shfl(nu, ((l & 7) << 3) | (l >> 3));
    }
    const float z = lse64(u);
    if (l == 0) logZT[n] = z / (float)TT;
}

// ---------------- Kernel D: bf16 scores -> final f32 output --------------
__global__ __launch_bounds__(128) void kD_final(const ushort* __restrict__ sc,
                                                const float* __restrict__ logZT,
                                                float* __restrict__ out) {
    __shared__ float dout[128 * SOUT];   // 24.6 KB
    const int tid = threadIdx.x;
    const long row0 = (long)blockIdx.x * 128;
    const long row = row0 + tid;
    const int n = (int)(row & (NN - 1));
    const float z = logZT[n];
    const ushort* srow = sc + row * SOUT;
    float st[48];
#pragma unroll
    for (int i = 0; i < 6; ++i) {
        const uint4 q = reinterpret_cast<const uint4*>(srow)[i];
        const unsigned wv[4] = {q.x, q.y, q.z, q.w};
#pragma unroll
        for (int t = 0; t < 4; ++t) {
            st[8 * i + 2 * t]     = __uint_as_float(wv[t] << 16);
            st[8 * i + 2 * t + 1] = __uint_as_float(wv[t] & 0xffff0000u);
        }
    }
    float* a = &dout[tid * SOUT];
#pragma unroll
    for (int c = 0; c < 40; ++c) a[c] = st[sidx(c)] - z;
    const float y40 = st[40], y41 = st[41], y42 = st[42], y43 = st[43], y44 = st[44];
    const float m3 = fmaxf(fmaxf(y40, y41), y42);
    const float l3 = m3 + __logf(__expf(y40 - m3) + __expf(y41 - m3) + __expf(y42 - m3));
    a[40] = y40 - l3; a[41] = y41 - l3; a[42] = y42 - l3;
    const float mA = fmaxf(y40, y43);
    const float lA = mA + __logf(__expf(y40 - mA) + __expf(y43 - mA));
    a[43] = y40 - lA; a[44] = y43 - lA;
    a[45] = 0.f;
    const float mB = fmaxf(y40, y44);
    const float lB = mB + __logf(__expf(y40 - mB) + __expf(y44 - mB));
    a[46] = y40 - lB; a[47] = y44 - lB;
    __syncthreads();
    const float4* sf = reinterpret_cast<const float4*>(dout);
    float4* df = reinterpret_cast<float4*>(out + row0 * SOUT);
#pragma unroll
    for (int kq = 0; kq < 12; ++kq)
        df[kq * 128 + tid] = sf[kq * 128 + tid];
}

extern "C" void kernel_launch(void* const* d_in, const int* in_sizes, int n_in,
                              void* d_out, int out_size, void* d_ws, size_t ws_size,
                              hipStream_t stream) {
    const float* x = (const float*)d_in[0];
    const float* W = (const float*)d_in[1];
    const float* b = (const float*)d_in[2];
    float* out = (float*)d_out;

    ushort* sc   = (ushort*)d_ws;                          // 49.15 MB
    float* gbuf  = (float*)((char*)d_ws + 49152000);       // 2.62 MB
    float* logZT = gbuf + (long)NN * CHUNKS * 64;          // 256 f32
    float* b48   = logZT + NN;                             // 48 f32
    ushort* Whi  = (ushort*)(b48 + SOUT);                  // 24 KB

    hipLaunchKernelGGL(kPrep, dim3(SOUT), dim3(DD), 0, stream, W, b, Whi, b48);
    hipLaunchKernelGGL(kA_mfma, dim3((TT * NN) / 128), dim3(512), 0, stream, x, Whi, b48, sc);
    hipLaunchKernelGGL(kB_scan, dim3(NN, CHUNKS), dim3(64), 0, stream, sc, gbuf);
    hipLaunchKernelGGL(kC_combine, dim3(NN), dim3(64), 0, stream, gbuf, logZT);
    hipLaunchKernelGGL(kD_final, dim3((TT * NN) / 128), dim3(128), 0, stream, sc, logZT, out);
}

// Round 14
// 224.865 us; speedup vs baseline: 1.8223x; 1.8223x over previous
//
#include <hip/hip_runtime.h>
#include <hip/hip_bf16.h>
#include <math.h>

#define TT 2000
#define NN 256
#define DD 256
#define SS 45
#define SOUT 48
#define NTRANS_C 40
#define CHUNKS 40
#define CLEN 50   // TT / CHUNKS
#define BK 32     // x K-chunk (floats)
#define NCH (DD / BK)   // 8 chunks
#define XPAD 40   // bf16 x-tile row stride (ushorts): 80 B -> bank-rotating, 16B-aligned

typedef __attribute__((ext_vector_type(8))) short bf16x8;
typedef __attribute__((ext_vector_type(4))) float f32x4;

__device__ inline ushort f2bf_rne(float f) {
    unsigned u = __float_as_uint(f);
    unsigned r = u + 0x7fffu + ((u >> 16) & 1u);
    return (ushort)(r >> 16);
}
// packed f32x2 -> bf16x2 (RNE), single HW instr
__device__ __forceinline__ int cvtpk(float lo, float hi) {
    int r;
    asm("v_cvt_pk_bf16_f32 %0, %1, %2" : "=v"(r) : "v"(lo), "v"(hi));
    return r;
}
// score-buffer storage permutation (kB reads b64+b32)
__device__ __host__ __forceinline__ constexpr int sidx(int c) {
    return (c < 32) ? (4 * (c & 7) + (c >> 3))
         : (c < 36) ? (32 + 2 * (c - 32))
         : (c < 40) ? (32 + 2 * (c - 36) + 1)
         : c;
}
// LDS W swizzle: 16B slot index XORed with (row&7); idx in ushorts.
__device__ __forceinline__ int swz_idx(int s, int koff) {
    return s * DD + ((((koff >> 3) ^ (s & 7)) << 3) | (koff & 7));
}

// ---------------- Prep: W -> bf16 (RNE), pad to 48 rows; pad b ----------
__global__ __launch_bounds__(256) void kPrep(const float* __restrict__ W,
                                             const float* __restrict__ b,
                                             ushort* __restrict__ Whi,
                                             float* __restrict__ b48) {
    const int s = blockIdx.x;   // 0..47
    const int k = threadIdx.x;  // 0..255
    const float wv = (s < SS) ? W[s * DD + k] : 0.f;
    Whi[s * DD + k] = f2bf_rne(wv);
    if (k == 0) b48[s] = (s < SS) ? b[s] : 0.f;
}

// ---------------- Kernel A: bf16-staged, bank-clean, high-occupancy ------
// R13 profile: LDS-pipe-bound (VALU 11%, MFMA 6%, 21M bank-conflict cyc).
// Fix: x staged as bf16 (reg->cvt->ds_write_b64), padded rows (XPAD=40)
// for conflict-free writes+reads; LDS 72->34 KB (3-4 blocks/CU); plain
// loads with compiler-counted vmcnt (2-deep prefetch, static pf[] index).
__global__ __launch_bounds__(512, 6) void kA_mfma(const float* __restrict__ x,
                                                  const ushort* __restrict__ Whi,
                                                  const float* __restrict__ b48,
                                                  ushort* __restrict__ sc) {
    __shared__ ushort Wl[SOUT * DD];        // 24 KB, slot-swizzled
    __shared__ ushort xw[8][16 * XPAD];     // 10.24 KB, per-wave bf16 x-tiles
    const int tid = threadIdx.x;
    // stage W once
    for (int idx = tid; idx < SOUT * (DD / 8); idx += 512) {
        const int s = idx >> 5;
        const int c8 = (idx & 31) * 8;
        const uint4 v = *reinterpret_cast<const uint4*>(Whi + s * DD + c8);
        *reinterpret_cast<uint4*>(&Wl[swz_idx(s, c8)]) = v;
    }
    __syncthreads();

    const int l = tid & 63, w = tid >> 6;
    const long m0 = (long)blockIdx.x * 128;
    const int r16 = l & 15;   // A row / C col
    const int kg = l >> 4;    // k-group 0..3
    // loader mapping: lane covers rows w*16+(l>>3) and +8, cols (l&7)*4..+3
    const int lrow = l >> 3;
    const int lcol = (l & 7) * 4;
    const float* xp = x + (m0 + w * 16 + lrow) * DD + lcol;
    const float* xq = xp + 8 * DD;
    ushort* xs = xw[w];
    int2* xw0 = reinterpret_cast<int2*>(&xs[lrow * XPAD + lcol]);        // 8B-aligned
    int2* xw1 = reinterpret_cast<int2*>(&xs[(lrow + 8) * XPAD + lcol]);
    const bf16x8* xrd = reinterpret_cast<const bf16x8*>(&xs[r16 * XPAD + kg * 8]); // 16B-aligned

    f32x4 acc[3] = {{0, 0, 0, 0}, {0, 0, 0, 0}, {0, 0, 0, 0}};

    // 2-deep register prefetch; compiler emits counted vmcnt before each use
    float4 pf[2][2];
    pf[0][0] = *reinterpret_cast<const float4*>(xp + 0);
    pf[0][1] = *reinterpret_cast<const float4*>(xq + 0);
    pf[1][0] = *reinterpret_cast<const float4*>(xp + BK);
    pf[1][1] = *reinterpret_cast<const float4*>(xq + BK);

#pragma unroll
    for (int c = 0; c < NCH; ++c) {
        const float4 pa = pf[c & 1][0];
        const float4 qa = pf[c & 1][1];
        // cvt to bf16 and stage into padded LDS tile (same-wave DS ops are
        // processed in order -> no explicit wait needed before the read)
        xw0->x = cvtpk(pa.x, pa.y);
        xw0->y = cvtpk(pa.z, pa.w);
        xw1->x = cvtpk(qa.x, qa.y);
        xw1->y = cvtpk(qa.z, qa.w);
        if (c + 2 < NCH) {   // refill the slot just consumed
            pf[c & 1][0] = *reinterpret_cast<const float4*>(xp + (c + 2) * BK);
            pf[c & 1][1] = *reinterpret_cast<const float4*>(xq + (c + 2) * BK);
        }
        __builtin_amdgcn_sched_barrier(0);   // pin writes before fragment reads
        const bf16x8 a = *xrd;
        const int koff = c * BK + kg * 8;
        const bf16x8 b0 = *reinterpret_cast<const bf16x8*>(&Wl[swz_idx(0 * 16 + r16, koff)]);
        const bf16x8 b1 = *reinterpret_cast<const bf16x8*>(&Wl[swz_idx(1 * 16 + r16, koff)]);
        const bf16x8 b2 = *reinterpret_cast<const bf16x8*>(&Wl[swz_idx(2 * 16 + r16, koff)]);
        acc[0] = __builtin_amdgcn_mfma_f32_16x16x32_bf16(a, b0, acc[0], 0, 0, 0);
        acc[1] = __builtin_amdgcn_mfma_f32_16x16x32_bf16(a, b1, acc[1], 0, 0, 0);
        acc[2] = __builtin_amdgcn_mfma_f32_16x16x32_bf16(a, b2, acc[2], 0, 0, 0);
    }

    // ---- epilogue: LDS-staged coalesced score store (reuses Wl) ----
    __syncthreads();   // all waves done reading W / own x-tile
    ushort* se = Wl;   // 128*48 u16 = 12.3 KB <= 24 KB
#pragma unroll
    for (int jt = 0; jt < 3; ++jt) {
        const int col = jt * 16 + r16;
        const float bias = b48[col];
        int si;
        if (jt < 2) si = 4 * (col & 7) + (col >> 3);
        else if (r16 < 8) si = (r16 < 4) ? (32 + 2 * r16) : (32 + 2 * (r16 - 4) + 1);
        else si = 40 + (r16 - 8);
#pragma unroll
        for (int r = 0; r < 4; ++r) {
            const int lr = w * 16 + kg * 4 + r;   // 0..127 (block-local row)
            const float y = acc[jt][r] + bias;
            float v;
            if (col < NTRANS_C) {
                const float e = __expf(2.f * y);
                v = 5.f * (1.f - 2.f / (e + 1.f));   // 5*tanh(y)
            } else {
                v = y;
            }
            se[lr * SOUT + si] = f2bf_rne(v);
        }
    }
    __syncthreads();
    // coalesced burst: 768 uint4 (12.3 KB), 1 KB per wave-instruction
    const uint4* su = reinterpret_cast<const uint4*>(se);
    uint4* du = reinterpret_cast<uint4*>(sc + m0 * SOUT);
    du[tid] = su[tid];
    if (tid < 256) du[512 + tid] = su[512 + tid];
}

// ---------------- DPP / swizzle cross-lane helpers -----------------------
#define DPP_XOR1 0xB1  // quad_perm(1,0,3,2)
#define DPP_XOR2 0x4E  // quad_perm(2,3,0,1)

__device__ inline float fmax_x1(float v) {
    const int d = __builtin_amdgcn_mov_dpp(__float_as_int(v), DPP_XOR1, 0xF, 0xF, true);
    return fmaxf(v, __int_as_float(d));
}
__device__ inline float fmax_x2(float v) {
    const int d = __builtin_amdgcn_mov_dpp(__float_as_int(v), DPP_XOR2, 0xF, 0xF, true);
    return fmaxf(v, __int_as_float(d));
}
__device__ inline float add_x1(float v) {
    const int d = __builtin_amdgcn_mov_dpp(__float_as_int(v), DPP_XOR1, 0xF, 0xF, true);
    return v + __int_as_float(d);
}
__device__ inline float add_x2(float v) {
    const int d = __builtin_amdgcn_mov_dpp(__float_as_int(v), DPP_XOR2, 0xF, 0xF, true);
    return v + __int_as_float(d);
}
__device__ inline float swz4(float v) {   // lane ^ 4
    return __int_as_float(__builtin_amdgcn_ds_swizzle(__float_as_int(v), 0x101F));
}
__device__ inline float fmax_x4(float v) { return fmaxf(v, swz4(v)); }
__device__ inline float add_x4(float v) { return v + swz4(v); }
__device__ inline float sum8(float v) { return add_x4(add_x2(add_x1(v))); }
__device__ inline float max8(float v) { return fmax_x4(fmax_x2(fmax_x1(v))); }
__device__ inline float gat_k(float v) {
    return __int_as_float(__builtin_amdgcn_ds_swizzle(__float_as_int(v), 0x001B));
}

// ---------------- Kernel B: per-(n,chunk) 8x8 log transfer matrix ----------
__global__ __launch_bounds__(64) void kB_scan(const ushort* __restrict__ sc,
                                              float* __restrict__ gbuf) {
    const int n = blockIdx.x;
    const int c = blockIdx.y;
    const int l = threadIdx.x;
    const int col = l >> 3;
    const int j = l & 7;
    const int k = j & 3;
    float m = (j == col) ? 0.f : -60.f;   // finite "-inf"
    const long stride = (long)NN * SOUT;  // in u16 elements
    const ushort* sp = sc + ((long)(c * CLEN) * NN + n) * SOUT;

    uint2 dv = *reinterpret_cast<const uint2*>(sp + 4 * j);
    unsigned dab = *reinterpret_cast<const unsigned*>(sp + 32 + 2 * k);

    for (int t = 0; t < CLEN; ++t) {
        const ushort* np = sp + stride;
        uint2 nv;
        unsigned nab;
        if (t + 1 < CLEN) {   // prefetch next step's scores
            nv = *reinterpret_cast<const uint2*>(np + 4 * j);
            nab = *reinterpret_cast<const unsigned*>(np + 32 + 2 * k);
        }
        const float c0 = __uint_as_float(dv.x << 16);
        const float c1 = __uint_as_float(dv.x & 0xffff0000u);
        const float c2 = __uint_as_float(dv.y << 16);
        const float c3 = __uint_as_float(dv.y & 0xffff0000u);
        const float ca = __uint_as_float(dab << 16);
        const float cb = __uint_as_float(dab & 0xffff0000u);
        const float E0 = __expf(c0), E1 = __expf(c1), E2 = __expf(c2), E3 = __expf(c3);
        const float Ea = __expf(ca), Eb = __expf(cb);
        const float Mq = fmax_x2(fmax_x1(m));   // quad-local max (2 DPP)
        const float MqX = swz4(Mq);             // other quad's max (parallel)
        const float e = __expf(m - Mq);
        const float corr = __expf(MqX - Mq);    // cross-quad rescale
        const float p0l = add_x2(add_x1(e * E0));
        const float p1l = add_x2(add_x1(e * E1));
        const float p2l = add_x2(add_x1(e * E2));
        const float p3l = add_x2(add_x1(e * E3));
        const float p0 = fmaf(corr, swz4(p0l), p0l);
        const float p1 = fmaf(corr, swz4(p1l), p1l);
        const float p2 = fmaf(corr, swz4(p2l), p2l);
        const float p3 = fmaf(corr, swz4(p3l), p3l);
        const float Sb = fmaf(corr * gat_k(e), Ea, e * Eb);
        const float Slow = (j < 2) ? ((j == 0) ? p0 : p1)
                                   : ((j == 2) ? p2 : p3);
        const float S = (j < 4) ? Slow : Sb;
        m = Mq + __logf(S);
        dv = nv; dab = nab;
        sp = np;
    }
    gbuf[((long)(n * CHUNKS + c)) * 64 + l] = m;
}

// ---------------- butterfly lse helpers for kC ----------------
__device__ inline float lse8(float v) {
    const float m = max8(v);
    return m + __logf(sum8(__expf(v - m)));
}
__device__ inline float lse64(float v) {
    float m = v;
#pragma unroll
    for (int d = 1; d < 64; d <<= 1) m = fmaxf(m, __shfl_xor(m, d));
    float e = __expf(v - m);
#pragma unroll
    for (int d = 1; d < 64; d <<= 1) e += __shfl_xor(e, d);
    return m + __logf(e);
}

// ---------------- Kernel C: fold chunk matrices, emit logZ/T -------------
__global__ __launch_bounds__(64) void kC_combine(const float* __restrict__ gbuf,
                                                 float* __restrict__ logZT) {
    const int n = blockIdx.x;
    const int l = threadIdx.x;
    const int gi = (l & 7) * 8 + (l >> 3);
    float g[CHUNKS];
#pragma unroll
    for (int c = 0; c < CHUNKS; ++c)
        g[c] = gbuf[((long)(n * CHUNKS + c)) * 64 + gi];
    float u = -logf(8.f);
#pragma unroll
    for (int c = 0; c < CHUNKS; ++c) {
        const float nu = lse8(g[c] + u);
        u = __shfl(nu, ((l & 7) << 3) | (l >> 3));
    }
    const float z = lse64(u);
    if (l == 0) logZT[n] = z / (float)TT;
}

// ---------------- Kernel D: bf16 scores -> final f32 output --------------
__global__ __launch_bounds__(128) void kD_final(const ushort* __restrict__ sc,
                                                const float* __restrict__ logZT,
                                                float* __restrict__ out) {
    __shared__ float dout[128 * SOUT];   // 24.6 KB
    const int tid = threadIdx.x;
    const long row0 = (long)blockIdx.x * 128;
    const long row = row0 + tid;
    const int n = (int)(row & (NN - 1));
    const float z = logZT[n];
    const ushort* srow = sc + row * SOUT;
    float st[48];
#pragma unroll
    for (int i = 0; i < 6; ++i) {
        const uint4 q = reinterpret_cast<const uint4*>(srow)[i];
        const unsigned wv[4] = {q.x, q.y, q.z, q.w};
#pragma unroll
        for (int t = 0; t < 4; ++t) {
            st[8 * i + 2 * t]     = __uint_as_float(wv[t] << 16);
            st[8 * i + 2 * t + 1] = __uint_as_float(wv[t] & 0xffff0000u);
        }
    }
    float* a = &dout[tid * SOUT];
#pragma unroll
    for (int c = 0; c < 40; ++c) a[c] = st[sidx(c)] - z;
    const float y40 = st[40], y41 = st[41], y42 = st[42], y43 = st[43], y44 = st[44];
    const float m3 = fmaxf(fmaxf(y40, y41), y42);
    const float l3 = m3 + __logf(__expf(y40 - m3) + __expf(y41 - m3) + __expf(y42 - m3));
    a[40] = y40 - l3; a[41] = y41 - l3; a[42] = y42 - l3;
    const float mA = fmaxf(y40, y43);
    const float lA = mA + __logf(__expf(y40 - mA) + __expf(y43 - mA));
    a[43] = y40 - lA; a[44] = y43 - lA;
    a[45] = 0.f;
    const float mB = fmaxf(y40, y44);
    const float lB = mB + __logf(__expf(y40 - mB) + __expf(y44 - mB));
    a[46] = y40 - lB; a[47] = y44 - lB;
    __syncthreads();
    const float4* sf = reinterpret_cast<const float4*>(dout);
    float4* df = reinterpret_cast<float4*>(out + row0 * SOUT);
#pragma unroll
    for (int kq = 0; kq < 12; ++kq)
        df[kq * 128 + tid] = sf[kq * 128 + tid];
}

extern "C" void kernel_launch(void* const* d_in, const int* in_sizes, int n_in,
                              void* d_out, int out_size, void* d_ws, size_t ws_size,
                              hipStream_t stream) {
    const float* x = (const float*)d_in[0];
    const float* W = (const float*)d_in[1];
    const float* b = (const float*)d_in[2];
    float* out = (float*)d_out;

    ushort* sc   = (ushort*)d_ws;                          // 49.15 MB
    float* gbuf  = (float*)((char*)d_ws + 49152000);       // 2.62 MB
    float* logZT = gbuf + (long)NN * CHUNKS * 64;          // 256 f32
    float* b48   = logZT + NN;                             // 48 f32
    ushort* Whi  = (ushort*)(b48 + SOUT);                  // 24 KB

    hipLaunchKernelGGL(kPrep, dim3(SOUT), dim3(DD), 0, stream, W, b, Whi, b48);
    hipLaunchKernelGGL(kA_mfma, dim3((TT * NN) / 128), dim3(512), 0, stream, x, Whi, b48, sc);
    hipLaunchKernelGGL(kB_scan, dim3(NN, CHUNKS), dim3(64), 0, stream, sc, gbuf);
    hipLaunchKernelGGL(kC_combine, dim3(NN), dim3(64), 0, stream, gbuf, logZT);
    hipLaunchKernelGGL(kD_final, dim3((TT * NN) / 128), dim3(128), 0, stream, sc, logZT, out);
}